// Round 1
// baseline (461.784 us; speedup 1.0000x reference)
//
#include <hip/hip_runtime.h>
#include <hip/hip_bf16.h>

#define NN 8192
#define KF 512
#define FF 64
#define GAT_ALPHA 0.2f
#define MSHIFT 20.0f   // safe upper bound on max_j e2[j]; softmax is shift-invariant

typedef __attribute__((ext_vector_type(8))) __bf16 bf16x8;
typedef __attribute__((ext_vector_type(4))) float f32x4;

// ---------------------------------------------------------------------------
// Kernel A: h = x@W (fp32 accum), e1 = h@a1, e2 = h@a2 (fp32),
//           ht = h^T in bf16 [64][8192] for MFMA B-operand loads.
// 128 blocks x 256 threads; each block does 64 rows; thread = 4 rows x 4 feats.
// ---------------------------------------------------------------------------
__global__ __launch_bounds__(256) void gat_linear(
    const float* __restrict__ x, const float* __restrict__ W,
    const float* __restrict__ av, __hip_bfloat16* __restrict__ ht,
    float* __restrict__ e1, float* __restrict__ e2)
{
    __shared__ float xs[32][68];      // [k][row], stride 68 -> 16B-aligned rows, balanced banks
    __shared__ float Ws[32][64];      // [k][f]
    __shared__ float ep[2][64][17];   // e1/e2 partials, padded stride 17

    const int t  = threadIdx.x;
    const int fq = t & 15;            // feature quad 0..15  (f = fq*4+v)
    const int rq = t >> 4;            // row quad 0..15      (r = rq*4+u)
    const int i0 = blockIdx.x * 64;

    float acc[4][4] = {};

    for (int kt = 0; kt < KF; kt += 32) {
        // stage x tile transposed: xs[k][r]
        {
            const int k = t & 31, r8 = t >> 5;
            #pragma unroll
            for (int m = 0; m < 8; ++m) {
                int r = r8 + 8 * m;
                xs[k][r] = x[(size_t)(i0 + r) * KF + kt + k];
            }
        }
        // stage W tile: Ws[k][f]
        {
            const int fw = t & 63, kq = t >> 6;
            #pragma unroll
            for (int m = 0; m < 8; ++m) {
                int k2 = kq + 4 * m;
                Ws[k2][fw] = W[(size_t)(kt + k2) * FF + fw];
            }
        }
        __syncthreads();
        #pragma unroll
        for (int kk = 0; kk < 32; kk += 4) {
            #pragma unroll
            for (int i = 0; i < 4; ++i) {
                f32x4 xv = *(const f32x4*)&xs[kk + i][rq * 4];
                f32x4 wv = *(const f32x4*)&Ws[kk + i][fq * 4];
                #pragma unroll
                for (int u = 0; u < 4; ++u)
                    #pragma unroll
                    for (int v = 0; v < 4; ++v)
                        acc[u][v] += xv[u] * wv[v];
            }
        }
        __syncthreads();
    }

    // write ht (bf16, transposed): 4 consecutive rows per feature -> 8B stores
    #pragma unroll
    for (int v = 0; v < 4; ++v) {
        int f = fq * 4 + v;
        union { ushort4 q; __hip_bfloat16 h[4]; } pk;
        #pragma unroll
        for (int u = 0; u < 4; ++u) pk.h[u] = __float2bfloat16(acc[u][v]);
        *(ushort4*)&ht[(size_t)f * NN + i0 + rq * 4] = pk.q;
    }

    // e1/e2 partials (fp32 h for accuracy of exp inputs)
    f32x4 a1v = *(const f32x4*)&av[fq * 4];
    f32x4 a2v = *(const f32x4*)&av[64 + fq * 4];
    #pragma unroll
    for (int u = 0; u < 4; ++u) {
        float s1 = 0.f, s2 = 0.f;
        #pragma unroll
        for (int v = 0; v < 4; ++v) {
            s1 += acc[u][v] * a1v[v];
            s2 += acc[u][v] * a2v[v];
        }
        ep[0][rq * 4 + u][fq] = s1;
        ep[1][rq * 4 + u][fq] = s2;
    }
    __syncthreads();
    if (t < 64) {
        float s1 = 0.f, s2 = 0.f;
        #pragma unroll
        for (int q = 0; q < 16; ++q) { s1 += ep[0][t][q]; s2 += ep[1][t][q]; }
        e1[i0 + t] = s1;
        e2[i0 + t] = s2;
    }
}

// ---------------------------------------------------------------------------
// Kernel B: masked softmax + attention@h via bf16 MFMA.
// 512 blocks x 256 threads; block = 16 output rows, sweeps all 8192 j in
// 64-wide tiles. Stage 1: adj int4 loads (depth-2 prefetch) -> p=exp(e-m)
// -> bf16 P-tile in LDS. Stage 2: 4 waves x 2 mfma_16x16x32_bf16 (A=P, B=hT).
// ---------------------------------------------------------------------------
__global__ __launch_bounds__(256) void gat_attn(
    const int* __restrict__ adj, const __hip_bfloat16* __restrict__ ht,
    const float* __restrict__ e1, const float* __restrict__ e2,
    float* __restrict__ out)
{
    __shared__ __hip_bfloat16 ps[16][72];  // P tile [row][j], stride 72 bf16 (36 words): balanced b128 banks
    __shared__ float l_red[16];

    const int t    = threadIdx.x;
    const int ii   = t >> 4;        // row 0..15 (stage-1 role)
    const int jq   = t & 15;        // j group (4 j's each)
    const int i0   = blockIdx.x * 16;
    const int lane = t & 63;
    const int wv   = t >> 6;        // wave id = feature slice
    const int n16  = lane & 15;
    const int quad = lane >> 4;

    const float e1i = e1[i0 + ii];
    float ms = e1i + MSHIFT;
    const float mi = ms > 0.f ? ms : GAT_ALPHA * ms;

    if (t < 16) l_red[t] = 0.f;

    const int*   arow = adj + (size_t)(i0 + ii) * NN + jq * 4;
    const float* e2p  = e2 + jq * 4;
    const __hip_bfloat16* htp = ht + (size_t)(wv * 16 + n16) * NN + quad * 8;
    const __hip_bfloat16* psa = &ps[n16][quad * 8];
    const __hip_bfloat16* psb = &ps[n16][32 + quad * 8];

    // depth-2 prefetch (register double-buffer, manually unrolled x2)
    int4   a0 = *(const int4*)(arow);
    float4 v0 = *(const float4*)(e2p);
    int4   a1 = *(const int4*)(arow + 64);
    float4 v1 = *(const float4*)(e2p + 64);

    float lpart = 0.f;
    f32x4 dacc = {0.f, 0.f, 0.f, 0.f};

    __syncthreads();

#define GAT_TILE(AV, EV, TILE, PF_OFF)                                         \
    {                                                                          \
        int4 a_ = (AV); float4 e_ = (EV);                                      \
        if ((TILE) + (PF_OFF) < 128) {                                         \
            (AV) = *(const int4*)(arow + ((TILE) + (PF_OFF)) * 64);            \
            (EV) = *(const float4*)(e2p + ((TILE) + (PF_OFF)) * 64);           \
        }                                                                      \
        union { uint2 u; __hip_bfloat16 h[4]; } pk;                            \
        float s_, p_;                                                          \
        s_ = e1i + e_.x; s_ = s_ > 0.f ? s_ : GAT_ALPHA * s_;                  \
        p_ = (a_.x > 0) ? __expf(s_ - mi) : 0.f;                              \
        pk.h[0] = __float2bfloat16(p_); lpart += __bfloat162float(pk.h[0]);    \
        s_ = e1i + e_.y; s_ = s_ > 0.f ? s_ : GAT_ALPHA * s_;                  \
        p_ = (a_.y > 0) ? __expf(s_ - mi) : 0.f;                              \
        pk.h[1] = __float2bfloat16(p_); lpart += __bfloat162float(pk.h[1]);    \
        s_ = e1i + e_.z; s_ = s_ > 0.f ? s_ : GAT_ALPHA * s_;                  \
        p_ = (a_.z > 0) ? __expf(s_ - mi) : 0.f;                              \
        pk.h[2] = __float2bfloat16(p_); lpart += __bfloat162float(pk.h[2]);    \
        s_ = e1i + e_.w; s_ = s_ > 0.f ? s_ : GAT_ALPHA * s_;                  \
        p_ = (a_.w > 0) ? __expf(s_ - mi) : 0.f;                              \
        pk.h[3] = __float2bfloat16(p_); lpart += __bfloat162float(pk.h[3]);    \
        *(uint2*)&ps[ii][jq * 4] = pk.u;                                       \
        __syncthreads();                                                       \
        bf16x8 af0 = *(const bf16x8*)psa;                                      \
        bf16x8 af1 = *(const bf16x8*)psb;                                      \
        bf16x8 bf0 = *(const bf16x8*)(htp + (size_t)(TILE) * 64);              \
        bf16x8 bf1 = *(const bf16x8*)(htp + (size_t)(TILE) * 64 + 32);         \
        dacc = __builtin_amdgcn_mfma_f32_16x16x32_bf16(af0, bf0, dacc, 0, 0, 0);\
        dacc = __builtin_amdgcn_mfma_f32_16x16x32_bf16(af1, bf1, dacc, 0, 0, 0);\
        __syncthreads();                                                       \
    }

    for (int tile = 0; tile < 128; tile += 2) {
        GAT_TILE(a0, v0, tile, 2)
        GAT_TILE(a1, v1, tile + 1, 2)
    }
#undef GAT_TILE

    atomicAdd(&l_red[ii], lpart);
    __syncthreads();

    // epilogue: D layout col=lane&15, row=quad*4+reg (m89-verified)
    #pragma unroll
    for (int r = 0; r < 4; ++r) {
        int row = quad * 4 + r;
        float hv = dacc[r] / l_red[row];
        float o = hv > 0.f ? hv : __expf(hv) - 1.f;  // elu
        out[(size_t)(i0 + row) * FF + wv * 16 + n16] = o;
    }
}

extern "C" void kernel_launch(void* const* d_in, const int* in_sizes, int n_in,
                              void* d_out, int out_size, void* d_ws, size_t ws_size,
                              hipStream_t stream) {
    const float* x   = (const float*)d_in[0];
    const int*   adj = (const int*)d_in[1];
    const float* W   = (const float*)d_in[2];
    const float* av  = (const float*)d_in[3];
    float* out = (float*)d_out;

    // ws layout: ht bf16 [64][8192] (1 MB) | e1 f32[8192] | e2 f32[8192]
    char* wsb = (char*)d_ws;
    __hip_bfloat16* ht = (__hip_bfloat16*)wsb;
    float* e1 = (float*)(wsb + (1 << 20));
    float* e2 = e1 + NN;

    gat_linear<<<128, 256, 0, stream>>>(x, W, av, ht, e1, e2);
    gat_attn<<<512, 256, 0, stream>>>(adj, ht, e1, e2, out);
}